// Round 1
// baseline (1026.476 us; speedup 1.0000x reference)
//
#include <hip/hip_runtime.h>
#include <hip/hip_bf16.h>
#include <cstdint>

#define N_SUPPORT 131072
#define NUM_CLASSES 1024
#define DIM 512
#define LN_EPS 1e-5f

typedef __attribute__((ext_vector_type(8))) short bf16x8;
typedef __attribute__((ext_vector_type(4))) float f32x4;

__device__ __forceinline__ unsigned short f2bf(float f) {
  union { float f; uint32_t u; } c; c.f = f;
  uint32_t u = c.u;
  u += 0x7fffu + ((u >> 16) & 1u);
  return (unsigned short)(u >> 16);
}
__device__ __forceinline__ float bf2f(unsigned short h) {
  union { uint32_t u; float f; } c; c.u = ((uint32_t)h) << 16;
  return c.f;
}

// async global->LDS, 16B per lane; LDS dest must be wave-uniform base (+lane*16)
__device__ __forceinline__ void gload16(const void* g, void* l) {
  __builtin_amdgcn_global_load_lds((const __attribute__((address_space(1))) void*)g,
                                   (__attribute__((address_space(3))) void*)l,
                                   16, 0, 0);
}

// ---------------- cast X f32 -> bf16 ----------------
__global__ void k_cast_x(const float* __restrict__ x, unsigned short* __restrict__ xb) {
  const size_t i = ((size_t)blockIdx.x * blockDim.x + threadIdx.x) * 8;
  float4 a = *(const float4*)(x + i);
  float4 b = *(const float4*)(x + i + 4);
  uint4 o;
  o.x = (uint32_t)f2bf(a.x) | ((uint32_t)f2bf(a.y) << 16);
  o.y = (uint32_t)f2bf(a.z) | ((uint32_t)f2bf(a.w) << 16);
  o.z = (uint32_t)f2bf(b.x) | ((uint32_t)f2bf(b.y) << 16);
  o.w = (uint32_t)f2bf(b.z) | ((uint32_t)f2bf(b.w) << 16);
  *(uint4*)(xb + i) = o;
}

// ---------------- W1[l][k][n] f32 -> W1T[l][n][k] bf16 ----------------
__global__ void k_prep_w1t(const float* __restrict__ w1, unsigned short* __restrict__ w1t) {
  const int idx = blockIdx.x * 256 + threadIdx.x;      // 3*512*512 total
  const int l = idx >> 18;
  const int rem = idx & 262143;
  const int k = rem >> 9;
  const int n = rem & 511;
  w1t[((size_t)l * 512 + n) * 512 + k] = f2bf(w1[idx]);
}

// ---------------- counting sort of labels ----------------
__global__ void k_hist(const int* __restrict__ labels, int* __restrict__ counts) {
  const int i = blockIdx.x * 256 + threadIdx.x;
  atomicAdd(&counts[labels[i]], 1);
}

__global__ void k_scan(const int* __restrict__ counts, int* __restrict__ offs) {
  __shared__ int tmp[1024];
  const int t = threadIdx.x;
  const int myc = counts[t];
  tmp[t] = myc;
  __syncthreads();
  for (int o = 1; o < 1024; o <<= 1) {
    int v = (t >= o) ? tmp[t - o] : 0;
    __syncthreads();
    tmp[t] += v;
    __syncthreads();
  }
  offs[t] = tmp[t] - myc;   // exclusive
}

__global__ void k_scatter(const int* __restrict__ labels, const int* __restrict__ offs,
                          int* __restrict__ cursor, int* __restrict__ sorted) {
  const int i = blockIdx.x * 256 + threadIdx.x;
  const int c = labels[i];
  const int p = atomicAdd(&cursor[c], 1);
  sorted[offs[c] + p] = i;
}

// ---------------- fused GEMM1 + bias + LayerNorm + ReLU -> g (bf16) ----------------
// block: 256 threads (4 waves). tile: 64 rows x 512 cols (full row for LN).
// wave w covers cols [128w, 128w+128). MFMA 16x16x32 bf16, acc 4x8 frags.
__global__ __launch_bounds__(256, 2) void k_gemm1ln(
    const unsigned short* __restrict__ Xb, const unsigned short* __restrict__ W1T,
    const float* __restrict__ b1, const float* __restrict__ gamma, const float* __restrict__ beta,
    unsigned short* __restrict__ g, int l)
{
  __shared__ unsigned short sX[64 * 32];     // [row][k] 4KB
  __shared__ unsigned short sW[512 * 32];    // [n][k]  32KB
  __shared__ float wsum[4][64];
  __shared__ float wsq[4][64];
  __shared__ float smean[64];
  __shared__ float srstd[64];

  const int t = threadIdx.x;
  const int wv = t >> 6;
  const int lane = t & 63;
  const int lr = lane & 15;
  const int lq = lane >> 4;
  const int row0 = blockIdx.x * 64;

  const unsigned short* Wl = W1T + (size_t)l * 512 * 512;

  f32x4 acc[4][8];
  #pragma unroll
  for (int i = 0; i < 4; ++i)
    #pragma unroll
    for (int j = 0; j < 8; ++j) acc[i][j] = (f32x4){0.f, 0.f, 0.f, 0.f};

  const int xrow = t >> 2;          // 0..63
  const int ko8 = (t & 3) * 8;      // 0/8/16/24
  const unsigned short* xg = Xb + (size_t)(row0 + xrow) * 512 + ko8;
  unsigned short* sXw = sX + wv * 512;   // wave-uniform LDS base (1KB per wave)

  for (int ks = 0; ks < 16; ++ks) {
    const int kk = ks * 32;
    gload16(xg + kk, sXw);
    #pragma unroll
    for (int i = 0; i < 8; ++i) {
      const int n = i * 64 + (t >> 2);
      gload16(Wl + (size_t)n * 512 + kk + ko8, sW + (i * 256 + wv * 64) * 8);
    }
    __syncthreads();

    bf16x8 a[4], b[8];
    #pragma unroll
    for (int rf = 0; rf < 4; ++rf)
      a[rf] = *(const bf16x8*)(sX + (rf * 16 + lr) * 32 + lq * 8);
    #pragma unroll
    for (int cf = 0; cf < 8; ++cf)
      b[cf] = *(const bf16x8*)(sW + (wv * 128 + cf * 16 + lr) * 32 + lq * 8);

    #pragma unroll
    for (int rf = 0; rf < 4; ++rf)
      #pragma unroll
      for (int cf = 0; cf < 8; ++cf)
        acc[rf][cf] = __builtin_amdgcn_mfma_f32_16x16x32_bf16(a[rf], b[cf], acc[rf][cf], 0, 0, 0);
    __syncthreads();
  }

  // epilogue: bias + LN + ReLU + bf16 store
  float b1v[8], gv[8], bv[8];
  #pragma unroll
  for (int cf = 0; cf < 8; ++cf) {
    const int col = wv * 128 + cf * 16 + lr;
    b1v[cf] = b1[l * 512 + col];
    gv[cf] = gamma[l * 512 + col];
    bv[cf] = beta[l * 512 + col];
  }
  #pragma unroll
  for (int rf = 0; rf < 4; ++rf)
    #pragma unroll
    for (int cf = 0; cf < 8; ++cf)
      #pragma unroll
      for (int j = 0; j < 4; ++j) acc[rf][cf][j] += b1v[cf];

  // per-row partial sums over this wave's 128 cols; reduce across 16 lanes (same lq)
  #pragma unroll
  for (int rf = 0; rf < 4; ++rf) {
    #pragma unroll
    for (int j = 0; j < 4; ++j) {
      float s = 0.f, q = 0.f;
      #pragma unroll
      for (int cf = 0; cf < 8; ++cf) { float v = acc[rf][cf][j]; s += v; q += v * v; }
      #pragma unroll
      for (int m = 8; m >= 1; m >>= 1) { s += __shfl_xor(s, m, 16); q += __shfl_xor(q, m, 16); }
      if (lr == 0) { const int row = rf * 16 + lq * 4 + j; wsum[wv][row] = s; wsq[wv][row] = q; }
    }
  }
  __syncthreads();
  if (t < 64) {
    const float s = wsum[0][t] + wsum[1][t] + wsum[2][t] + wsum[3][t];
    const float q = wsq[0][t] + wsq[1][t] + wsq[2][t] + wsq[3][t];
    const float mean = s * (1.0f / 512.0f);
    const float var = q * (1.0f / 512.0f) - mean * mean;
    smean[t] = mean;
    srstd[t] = rsqrtf(var + LN_EPS);
  }
  __syncthreads();

  #pragma unroll
  for (int rf = 0; rf < 4; ++rf) {
    #pragma unroll
    for (int j = 0; j < 4; ++j) {
      const int row = rf * 16 + lq * 4 + j;
      const float mean = smean[row], rs = srstd[row];
      unsigned short* go = g + (size_t)(row0 + row) * 512 + wv * 128 + lr;
      #pragma unroll
      for (int cf = 0; cf < 8; ++cf) {
        float v = (acc[rf][cf][j] - mean) * rs * gv[cf] + bv[cf];
        v = fmaxf(v, 0.f);
        go[cf * 16] = f2bf(v);
      }
    }
  }
}

// ---------------- per-class gather-sum of g, divide by count -> M[l][c][d] f32 ----------------
__global__ void k_reduce(const unsigned short* __restrict__ g, const int* __restrict__ sorted,
                         const int* __restrict__ offs, const int* __restrict__ counts,
                         float* __restrict__ M, int l)
{
  __shared__ int sidx[256];
  const int c = blockIdx.x;
  const int t = threadIdx.x;
  const int beg = offs[c];
  const int n = counts[c];
  float a0 = 0.f, a1 = 0.f;
  for (int base = 0; base < n; base += 256) {
    const int m = min(256, n - base);
    __syncthreads();
    if (t < m) sidx[t] = sorted[beg + base + t];
    __syncthreads();
    for (int r = 0; r < m; ++r) {
      const uint32_t v = *(const uint32_t*)(g + (size_t)sidx[r] * 512 + t * 2);
      a0 += bf2f((unsigned short)(v & 0xffffu));
      a1 += bf2f((unsigned short)(v >> 16));
    }
  }
  const float inv = 1.0f / (float)max(n, 1);
  float* out = M + ((size_t)l * 1024 + c) * 512 + t * 2;
  out[0] = a0 * inv;
  out[1] = a1 * inv;
}

// ---------------- final small GEMM: out = sum_l w_l * (M_l @ W2_l + b2_l) ----------------
__global__ void k_final(const float* __restrict__ M, const float* __restrict__ W2,
                        const float* __restrict__ b2, const float* __restrict__ temps,
                        float* __restrict__ out)
{
  __shared__ float sA[64][17];
  __shared__ float sB[16][65];
  const int t = threadIdx.x;
  const int tx = t & 15, ty = t >> 4;
  const int bcol = blockIdx.x * 64;
  const int brow = blockIdx.y * 64;

  const float t0 = temps[0], t1 = temps[1], t2 = temps[2];
  const float mx = fmaxf(t0, fmaxf(t1, t2));
  const float e0 = expf(t0 - mx), e1 = expf(t1 - mx), e2 = expf(t2 - mx);
  const float inv = 1.f / (e0 + e1 + e2);
  const float w[3] = {e0 * inv, e1 * inv, e2 * inv};

  float acc[4][4] = {};
  for (int l = 0; l < 3; ++l) {
    for (int k0 = 0; k0 < 512; k0 += 16) {
      __syncthreads();
      #pragma unroll
      for (int i = 0; i < 4; ++i) {
        const int e = i * 256 + t;
        const int r = e >> 4, k = e & 15;
        sA[r][k] = M[((size_t)l * 1024 + brow + r) * 512 + k0 + k] * w[l];
      }
      #pragma unroll
      for (int i = 0; i < 4; ++i) {
        const int e = i * 256 + t;
        const int r = e >> 6, nn = e & 63;
        sB[r][nn] = W2[((size_t)l * 512 + k0 + r) * 512 + bcol + nn];
      }
      __syncthreads();
      #pragma unroll
      for (int kk = 0; kk < 16; ++kk) {
        float a[4], b[4];
        #pragma unroll
        for (int i = 0; i < 4; ++i) a[i] = sA[ty * 4 + i][kk];
        #pragma unroll
        for (int j = 0; j < 4; ++j) b[j] = sB[kk][tx * 4 + j];
        #pragma unroll
        for (int i = 0; i < 4; ++i)
          #pragma unroll
          for (int j = 0; j < 4; ++j) acc[i][j] += a[i] * b[j];
      }
    }
  }
  #pragma unroll
  for (int j = 0; j < 4; ++j) {
    const int col = bcol + tx * 4 + j;
    const float bias = w[0] * b2[col] + w[1] * b2[512 + col] + w[2] * b2[1024 + col];
    #pragma unroll
    for (int i = 0; i < 4; ++i)
      out[(size_t)(brow + ty * 4 + i) * 512 + col] = acc[i][j] + bias;
  }
}

extern "C" void kernel_launch(void* const* d_in, const int* in_sizes, int n_in,
                              void* d_out, int out_size, void* d_ws, size_t ws_size,
                              hipStream_t stream)
{
  const float* X = (const float*)d_in[0];
  const int* labels = (const int*)d_in[1];
  const float* W1 = (const float*)d_in[2];
  const float* b1 = (const float*)d_in[3];
  const float* gamma = (const float*)d_in[4];
  const float* beta = (const float*)d_in[5];
  const float* W2 = (const float*)d_in[6];
  const float* b2 = (const float*)d_in[7];
  const float* temps = (const float*)d_in[8];
  float* out = (float*)d_out;

  char* ws = (char*)d_ws;
  size_t off = 0;
  auto alloc = [&](size_t bytes) -> char* {
    char* p = ws + off;
    off += (bytes + 255) & ~(size_t)255;
    return p;
  };
  unsigned short* Xb = (unsigned short*)alloc((size_t)N_SUPPORT * DIM * 2);   // 128 MB
  unsigned short* gbuf = (unsigned short*)alloc((size_t)N_SUPPORT * DIM * 2); // 128 MB (reused per level)
  unsigned short* W1T = (unsigned short*)alloc((size_t)3 * 512 * 512 * 2);
  float* M = (float*)alloc((size_t)3 * 1024 * 512 * 4);
  int* counts = (int*)alloc(2048 * 4);       // counts[1024] + cursor[1024], one memset
  int* cursor = counts + 1024;
  int* offs = (int*)alloc(1024 * 4);
  int* sorted = (int*)alloc((size_t)N_SUPPORT * 4);
  (void)cursor;

  hipMemsetAsync(counts, 0, 2048 * 4, stream);
  k_cast_x<<<32768, 256, 0, stream>>>(X, Xb);
  k_prep_w1t<<<3072, 256, 0, stream>>>(W1, W1T);
  k_hist<<<512, 256, 0, stream>>>(labels, counts);
  k_scan<<<1, 1024, 0, stream>>>(counts, offs);
  k_scatter<<<512, 256, 0, stream>>>(labels, offs, cursor, sorted);
  for (int l = 0; l < 3; ++l) {
    k_gemm1ln<<<2048, 256, 0, stream>>>(Xb, W1T, b1, gamma, beta, gbuf, l);
    k_reduce<<<1024, 256, 0, stream>>>(gbuf, sorted, offs, counts, M, l);
  }
  k_final<<<dim3(8, 16), 256, 0, stream>>>(M, W2, b2, temps, out);
}

// Round 2
// 954.264 us; speedup vs baseline: 1.0757x; 1.0757x over previous
//
#include <hip/hip_runtime.h>
#include <hip/hip_bf16.h>
#include <cstdint>

#define N_SUPPORT 131072
#define NUM_CLASSES 1024
#define DIM 512
#define LN_EPS 1e-5f

typedef __attribute__((ext_vector_type(8))) short bf16x8;
typedef __attribute__((ext_vector_type(4))) float f32x4;

__device__ __forceinline__ unsigned short f2bf(float f) {
  union { float f; uint32_t u; } c; c.f = f;
  uint32_t u = c.u;
  u += 0x7fffu + ((u >> 16) & 1u);
  return (unsigned short)(u >> 16);
}

// async global->LDS, 16B per lane; LDS dest must be wave-uniform base (+lane*16)
__device__ __forceinline__ void gload16(const void* g, void* l) {
  __builtin_amdgcn_global_load_lds((const __attribute__((address_space(1))) void*)g,
                                   (__attribute__((address_space(3))) void*)l,
                                   16, 0, 0);
}

// ---------------- counting sort of labels ----------------
__global__ void k_hist(const int* __restrict__ labels, int* __restrict__ counts) {
  const int i = blockIdx.x * 256 + threadIdx.x;
  atomicAdd(&counts[labels[i]], 1);
}

__global__ void k_scan(const int* __restrict__ counts, int* __restrict__ offs,
                       float* __restrict__ invc) {
  __shared__ int tmp[1024];
  const int t = threadIdx.x;
  const int myc = counts[t];
  tmp[t] = myc;
  __syncthreads();
  for (int o = 1; o < 1024; o <<= 1) {
    int v = (t >= o) ? tmp[t - o] : 0;
    __syncthreads();
    tmp[t] += v;
    __syncthreads();
  }
  offs[t] = tmp[t] - myc;   // exclusive
  invc[t] = 1.0f / (float)max(myc, 1);
}

__global__ void k_scatter(const int* __restrict__ labels, const int* __restrict__ offs,
                          int* __restrict__ cursor, int* __restrict__ sorted) {
  const int i = blockIdx.x * 256 + threadIdx.x;
  const int c = labels[i];
  const int p = atomicAdd(&cursor[c], 1);
  sorted[offs[c] + p] = i;
}

// ---------------- cast X f32 -> bf16, permuted into class-sorted row order ----------------
__global__ void k_cast_sorted(const float* __restrict__ x, const int* __restrict__ sorted,
                              const int* __restrict__ labels,
                              unsigned short* __restrict__ xb, int* __restrict__ scls) {
  const int p = blockIdx.x * 4 + (threadIdx.x >> 6);     // dest (sorted) row
  const int src = sorted[p];
  const int k = (threadIdx.x & 63) * 8;
  const float* xr = x + (size_t)src * DIM + k;
  float4 a = *(const float4*)(xr);
  float4 b = *(const float4*)(xr + 4);
  uint4 o;
  o.x = (uint32_t)f2bf(a.x) | ((uint32_t)f2bf(a.y) << 16);
  o.y = (uint32_t)f2bf(a.z) | ((uint32_t)f2bf(a.w) << 16);
  o.z = (uint32_t)f2bf(b.x) | ((uint32_t)f2bf(b.y) << 16);
  o.w = (uint32_t)f2bf(b.z) | ((uint32_t)f2bf(b.w) << 16);
  *(uint4*)(xb + (size_t)p * DIM + k) = o;
  if ((threadIdx.x & 63) == 0) scls[p] = labels[src];
}

// ---------------- W1[l][k][n] f32 -> W1T[l][n][k] bf16 ----------------
__global__ void k_prep_w1t(const float* __restrict__ w1, unsigned short* __restrict__ w1t) {
  const int idx = blockIdx.x * 256 + threadIdx.x;      // 3*512*512 total
  const int l = idx >> 18;
  const int rem = idx & 262143;
  const int k = rem >> 9;
  const int n = rem & 511;
  w1t[((size_t)l * 512 + n) * 512 + k] = f2bf(w1[idx]);
}

// ---------------- fused GEMM1 + bias + LayerNorm + ReLU + segment-sum -> M (atomic f32) ----
// block: 256 threads (4 waves). tile: 64 rows x 512 cols (full row for LN).
// rows are class-sorted, so the tile spans few contiguous class runs; each run's
// column sums are atomicAdd'ed into M[l][cls][col].
__global__ __launch_bounds__(256, 2) void k_gemm1lnred(
    const unsigned short* __restrict__ Xb, const unsigned short* __restrict__ W1T,
    const float* __restrict__ b1, const float* __restrict__ gamma, const float* __restrict__ beta,
    const int* __restrict__ scls_g, float* __restrict__ M, int l)
{
  __shared__ unsigned short sX[64 * 32];     // [row][k] 4KB
  __shared__ unsigned short sW[512 * 32];    // [n][k]  32KB
  __shared__ float wsum[4][64];
  __shared__ float wsq[4][64];
  __shared__ float smean[64];
  __shared__ float srstd[64];
  __shared__ int scls[64];
  __shared__ int run_start[65];
  __shared__ int run_cls[64];
  __shared__ int nruns_s;

  const int t = threadIdx.x;
  const int wv = t >> 6;
  const int lane = t & 63;
  const int lr = lane & 15;
  const int lq = lane >> 4;
  const int row0 = blockIdx.x * 64;

  const unsigned short* Wl = W1T + (size_t)l * 512 * 512;

  f32x4 acc[4][8];
  #pragma unroll
  for (int i = 0; i < 4; ++i)
    #pragma unroll
    for (int j = 0; j < 8; ++j) acc[i][j] = (f32x4){0.f, 0.f, 0.f, 0.f};

  const int xrow = t >> 2;          // 0..63
  const int ko8 = (t & 3) * 8;      // 0/8/16/24
  const unsigned short* xg = Xb + (size_t)(row0 + xrow) * 512 + ko8;
  unsigned short* sXw = sX + wv * 512;   // wave-uniform LDS base (1KB per wave)

  if (t < 64) scls[t] = scls_g[row0 + t];

  for (int ks = 0; ks < 16; ++ks) {
    const int kk = ks * 32;
    gload16(xg + kk, sXw);
    #pragma unroll
    for (int i = 0; i < 8; ++i) {
      const int n = i * 64 + (t >> 2);
      gload16(Wl + (size_t)n * 512 + kk + ko8, sW + (i * 256 + wv * 64) * 8);
    }
    __syncthreads();

    bf16x8 a[4], b[8];
    #pragma unroll
    for (int rf = 0; rf < 4; ++rf)
      a[rf] = *(const bf16x8*)(sX + (rf * 16 + lr) * 32 + lq * 8);
    #pragma unroll
    for (int cf = 0; cf < 8; ++cf)
      b[cf] = *(const bf16x8*)(sW + (wv * 128 + cf * 16 + lr) * 32 + lq * 8);

    #pragma unroll
    for (int rf = 0; rf < 4; ++rf)
      #pragma unroll
      for (int cf = 0; cf < 8; ++cf)
        acc[rf][cf] = __builtin_amdgcn_mfma_f32_16x16x32_bf16(a[rf], b[cf], acc[rf][cf], 0, 0, 0);
    __syncthreads();
  }

  // epilogue: bias + LN stats
  float b1v[8], gv[8], bv[8];
  #pragma unroll
  for (int cf = 0; cf < 8; ++cf) {
    const int col = wv * 128 + cf * 16 + lr;
    b1v[cf] = b1[l * 512 + col];
    gv[cf] = gamma[l * 512 + col];
    bv[cf] = beta[l * 512 + col];
  }
  #pragma unroll
  for (int rf = 0; rf < 4; ++rf)
    #pragma unroll
    for (int cf = 0; cf < 8; ++cf)
      #pragma unroll
      for (int j = 0; j < 4; ++j) acc[rf][cf][j] += b1v[cf];

  // per-row partial sums over this wave's 128 cols; reduce across 16 lanes (same lq)
  #pragma unroll
  for (int rf = 0; rf < 4; ++rf) {
    #pragma unroll
    for (int j = 0; j < 4; ++j) {
      float s = 0.f, q = 0.f;
      #pragma unroll
      for (int cf = 0; cf < 8; ++cf) { float v = acc[rf][cf][j]; s += v; q += v * v; }
      #pragma unroll
      for (int m = 8; m >= 1; m >>= 1) { s += __shfl_xor(s, m, 16); q += __shfl_xor(q, m, 16); }
      if (lr == 0) { const int row = rf * 16 + lq * 4 + j; wsum[wv][row] = s; wsq[wv][row] = q; }
    }
  }
  __syncthreads();
  if (t < 64) {
    const float s = wsum[0][t] + wsum[1][t] + wsum[2][t] + wsum[3][t];
    const float q = wsq[0][t] + wsq[1][t] + wsq[2][t] + wsq[3][t];
    const float mean = s * (1.0f / 512.0f);
    const float var = q * (1.0f / 512.0f) - mean * mean;
    smean[t] = mean;
    srstd[t] = rsqrtf(var + LN_EPS);
  }
  if (t == 0) {
    int n = 0;
    run_start[0] = 0;
    run_cls[0] = scls[0];
    for (int r = 1; r < 64; ++r) {
      if (scls[r] != scls[r - 1]) { ++n; run_start[n] = r; run_cls[n] = scls[r]; }
    }
    nruns_s = n + 1;
    run_start[n + 1] = 64;
  }
  __syncthreads();

  // finalize g = relu(LN(h)) in registers
  #pragma unroll
  for (int rf = 0; rf < 4; ++rf) {
    #pragma unroll
    for (int j = 0; j < 4; ++j) {
      const int row = rf * 16 + lq * 4 + j;
      const float mean = smean[row], rs = srstd[row];
      #pragma unroll
      for (int cf = 0; cf < 8; ++cf) {
        float v = (acc[rf][cf][j] - mean) * rs * gv[cf] + bv[cf];
        acc[rf][cf][j] = fmaxf(v, 0.f);
      }
    }
  }

  // per-run column sums -> atomicAdd into M[l][cls][col]
  const int nruns = nruns_s;
  float* Ml = M + (size_t)l * NUM_CLASSES * DIM;
  for (int r = 0; r < nruns; ++r) {
    const int rs = run_start[r], re = run_start[r + 1];
    const int cls = run_cls[r];
    float p[8];
    #pragma unroll
    for (int cf = 0; cf < 8; ++cf) p[cf] = 0.f;
    #pragma unroll
    for (int rf = 0; rf < 4; ++rf) {
      #pragma unroll
      for (int j = 0; j < 4; ++j) {
        const int row = rf * 16 + lq * 4 + j;
        if (row >= rs && row < re) {
          #pragma unroll
          for (int cf = 0; cf < 8; ++cf) p[cf] += acc[rf][cf][j];
        }
      }
    }
    #pragma unroll
    for (int cf = 0; cf < 8; ++cf) {
      p[cf] += __shfl_xor(p[cf], 16);
      p[cf] += __shfl_xor(p[cf], 32);
    }
    if (lq == 0) {
      #pragma unroll
      for (int cf = 0; cf < 8; ++cf)
        atomicAdd(&Ml[(size_t)cls * DIM + wv * 128 + cf * 16 + lr], p[cf]);
    }
  }
}

// ---------------- final small GEMM: out = sum_l w_l * ((M_l/cnt) @ W2_l + b2_l) ----------------
__global__ void k_final(const float* __restrict__ M, const float* __restrict__ W2,
                        const float* __restrict__ b2, const float* __restrict__ temps,
                        const float* __restrict__ invc, float* __restrict__ out)
{
  __shared__ float sA[64][17];
  __shared__ float sB[16][65];
  const int t = threadIdx.x;
  const int tx = t & 15, ty = t >> 4;
  const int bcol = blockIdx.x * 64;
  const int brow = blockIdx.y * 64;

  const float t0 = temps[0], t1 = temps[1], t2 = temps[2];
  const float mx = fmaxf(t0, fmaxf(t1, t2));
  const float e0 = expf(t0 - mx), e1 = expf(t1 - mx), e2 = expf(t2 - mx);
  const float inv = 1.f / (e0 + e1 + e2);
  const float w[3] = {e0 * inv, e1 * inv, e2 * inv};

  float acc[4][4] = {};
  for (int l = 0; l < 3; ++l) {
    for (int k0 = 0; k0 < 512; k0 += 16) {
      __syncthreads();
      #pragma unroll
      for (int i = 0; i < 4; ++i) {
        const int e = i * 256 + t;
        const int r = e >> 4, k = e & 15;
        sA[r][k] = M[((size_t)l * 1024 + brow + r) * 512 + k0 + k] * (w[l] * invc[brow + r]);
      }
      #pragma unroll
      for (int i = 0; i < 4; ++i) {
        const int e = i * 256 + t;
        const int r = e >> 6, nn = e & 63;
        sB[r][nn] = W2[((size_t)l * 512 + k0 + r) * 512 + bcol + nn];
      }
      __syncthreads();
      #pragma unroll
      for (int kk = 0; kk < 16; ++kk) {
        float a[4], b[4];
        #pragma unroll
        for (int i = 0; i < 4; ++i) a[i] = sA[ty * 4 + i][kk];
        #pragma unroll
        for (int j = 0; j < 4; ++j) b[j] = sB[kk][tx * 4 + j];
        #pragma unroll
        for (int i = 0; i < 4; ++i)
          #pragma unroll
          for (int j = 0; j < 4; ++j) acc[i][j] += a[i] * b[j];
      }
    }
  }
  #pragma unroll
  for (int j = 0; j < 4; ++j) {
    const int col = bcol + tx * 4 + j;
    const float bias = w[0] * b2[col] + w[1] * b2[512 + col] + w[2] * b2[1024 + col];
    #pragma unroll
    for (int i = 0; i < 4; ++i)
      out[(size_t)(brow + ty * 4 + i) * 512 + col] = acc[i][j] + bias;
  }
}

extern "C" void kernel_launch(void* const* d_in, const int* in_sizes, int n_in,
                              void* d_out, int out_size, void* d_ws, size_t ws_size,
                              hipStream_t stream)
{
  const float* X = (const float*)d_in[0];
  const int* labels = (const int*)d_in[1];
  const float* W1 = (const float*)d_in[2];
  const float* b1 = (const float*)d_in[3];
  const float* gamma = (const float*)d_in[4];
  const float* beta = (const float*)d_in[5];
  const float* W2 = (const float*)d_in[6];
  const float* b2 = (const float*)d_in[7];
  const float* temps = (const float*)d_in[8];
  float* out = (float*)d_out;

  char* ws = (char*)d_ws;
  size_t off = 0;
  auto alloc = [&](size_t bytes) -> char* {
    char* p = ws + off;
    off += (bytes + 255) & ~(size_t)255;
    return p;
  };
  unsigned short* Xb = (unsigned short*)alloc((size_t)N_SUPPORT * DIM * 2);   // 128 MB, class-sorted
  unsigned short* W1T = (unsigned short*)alloc((size_t)3 * 512 * 512 * 2);
  float* M = (float*)alloc((size_t)3 * 1024 * 512 * 4);                       // 6 MB, atomic target
  int* counts = (int*)alloc(2048 * 4);       // counts[1024] + cursor[1024], one memset
  int* cursor = counts + 1024;
  int* offs = (int*)alloc(1024 * 4);
  float* invc = (float*)alloc(1024 * 4);
  int* sorted = (int*)alloc((size_t)N_SUPPORT * 4);
  int* scls = (int*)alloc((size_t)N_SUPPORT * 4);

  hipMemsetAsync(counts, 0, 2048 * 4, stream);
  hipMemsetAsync(M, 0, (size_t)3 * 1024 * 512 * 4, stream);
  k_hist<<<512, 256, 0, stream>>>(labels, counts);
  k_scan<<<1, 1024, 0, stream>>>(counts, offs, invc);
  k_scatter<<<512, 256, 0, stream>>>(labels, offs, cursor, sorted);
  k_cast_sorted<<<32768, 256, 0, stream>>>(X, sorted, labels, Xb, scls);
  k_prep_w1t<<<3072, 256, 0, stream>>>(W1, W1T);
  for (int l = 0; l < 3; ++l) {
    k_gemm1lnred<<<2048, 256, 0, stream>>>(Xb, W1T, b1, gamma, beta, scls, M, l);
  }
  k_final<<<dim3(8, 16), 256, 0, stream>>>(M, W2, b2, temps, invc, out);
}

// Round 3
// 855.994 us; speedup vs baseline: 1.1992x; 1.1148x over previous
//
#include <hip/hip_runtime.h>
#include <hip/hip_bf16.h>
#include <cstdint>

#define N_SUPPORT 131072
#define NUM_CLASSES 1024
#define DIM 512
#define LN_EPS 1e-5f

typedef __attribute__((ext_vector_type(8))) short bf16x8;
typedef __attribute__((ext_vector_type(4))) float f32x4;

__device__ __forceinline__ unsigned short f2bf(float f) {
  union { float f; uint32_t u; } c; c.f = f;
  uint32_t u = c.u;
  u += 0x7fffu + ((u >> 16) & 1u);
  return (unsigned short)(u >> 16);
}

// async global->LDS, 16B per lane; LDS dest must be wave-uniform base (+lane*16)
__device__ __forceinline__ void gload16(const void* g, void* l) {
  __builtin_amdgcn_global_load_lds((const __attribute__((address_space(1))) void*)g,
                                   (__attribute__((address_space(3))) void*)l,
                                   16, 0, 0);
}

// ---------------- counting sort of labels ----------------
__global__ void k_hist(const int* __restrict__ labels, int* __restrict__ counts) {
  const int i = blockIdx.x * 256 + threadIdx.x;
  atomicAdd(&counts[labels[i]], 1);
}

__global__ void k_scan(const int* __restrict__ counts, int* __restrict__ offs,
                       float* __restrict__ invc) {
  __shared__ int tmp[1024];
  const int t = threadIdx.x;
  const int myc = counts[t];
  tmp[t] = myc;
  __syncthreads();
  for (int o = 1; o < 1024; o <<= 1) {
    int v = (t >= o) ? tmp[t - o] : 0;
    __syncthreads();
    tmp[t] += v;
    __syncthreads();
  }
  offs[t] = tmp[t] - myc;   // exclusive
  invc[t] = 1.0f / (float)max(myc, 1);
}

__global__ void k_scatter(const int* __restrict__ labels, const int* __restrict__ offs,
                          int* __restrict__ cursor, int* __restrict__ sorted) {
  const int i = blockIdx.x * 256 + threadIdx.x;
  const int c = labels[i];
  const int p = atomicAdd(&cursor[c], 1);
  sorted[offs[c] + p] = i;
}

// ---------------- cast X f32 -> bf16, class-sorted, GEMM-tile order ----------------
// XbT layout, 16B units: unit(tile, ks, g, rr) at elem offset
//   (tile*64 + ks*4 + g)*512 + rr*8     (tile: 64 sorted rows; k = ks*32 + g*8 + e)
__global__ void k_cast_sorted(const float* __restrict__ x, const int* __restrict__ sorted,
                              const int* __restrict__ labels,
                              unsigned short* __restrict__ xbt, int* __restrict__ scls) {
  const int tile = blockIdx.x;
  const int t = threadIdx.x;
  const int rr = t & 63, ksl = t >> 6;
  const int p = tile * 64 + rr;
  const int src = sorted[p];
  if (t < 64) scls[p] = labels[src];
  const float* xr = x + (size_t)src * DIM;
  #pragma unroll
  for (int kb = 0; kb < 4; ++kb) {
    const int ks = kb * 4 + ksl;
    float4 f[8];
    #pragma unroll
    for (int i = 0; i < 8; ++i) f[i] = *(const float4*)(xr + ks * 32 + i * 4);
    #pragma unroll
    for (int g = 0; g < 4; ++g) {
      uint4 o;
      o.x = (uint32_t)f2bf(f[g * 2].x) | ((uint32_t)f2bf(f[g * 2].y) << 16);
      o.y = (uint32_t)f2bf(f[g * 2].z) | ((uint32_t)f2bf(f[g * 2].w) << 16);
      o.z = (uint32_t)f2bf(f[g * 2 + 1].x) | ((uint32_t)f2bf(f[g * 2 + 1].y) << 16);
      o.w = (uint32_t)f2bf(f[g * 2 + 1].z) | ((uint32_t)f2bf(f[g * 2 + 1].w) << 16);
      *(uint4*)(xbt + ((size_t)(tile * 64 + ks * 4 + g)) * 512 + rr * 8) = o;
    }
  }
}

// ---------------- W1[l][k][n] f32 -> W1T tile order ----------------
// unit(l, ks, g, n) at elem offset ((l*16 + ks)*4 + g)*4096 + n*8
__global__ void k_prep_w1t(const float* __restrict__ w1, unsigned short* __restrict__ w1t) {
  const int i = blockIdx.x * 256 + threadIdx.x;      // 3*16*4*512 = 98304
  const int l = i >> 15;
  const int ks = (i >> 11) & 15;
  const int g = (i >> 9) & 3;
  const int n = i & 511;
  const float* src = w1 + ((size_t)l * 512 + ks * 32 + g * 8) * 512 + n;
  unsigned short v[8];
  #pragma unroll
  for (int e = 0; e < 8; ++e) v[e] = f2bf(src[(size_t)e * 512]);
  uint4 o;
  o.x = (uint32_t)v[0] | ((uint32_t)v[1] << 16);
  o.y = (uint32_t)v[2] | ((uint32_t)v[3] << 16);
  o.z = (uint32_t)v[4] | ((uint32_t)v[5] << 16);
  o.w = (uint32_t)v[6] | ((uint32_t)v[7] << 16);
  *(uint4*)(w1t + (size_t)i * 8) = o;
}

// ---------------- fused GEMM1 + bias + LayerNorm + ReLU + segment-sum (all levels) ----
// grid (3, 2048): x = level (adjacent blocks share the X tile), y = 64-row tile.
// block: 256 threads / 4 waves; wave wv owns cols [128wv, 128wv+128).
// LDS tile order [g][row] -> ds_read_b128 bank pattern 4*row%32 = conflict-free.
__global__ __launch_bounds__(256, 2) void k_gemm1lnred(
    const unsigned short* __restrict__ XbT, const unsigned short* __restrict__ W1T,
    const float* __restrict__ b1, const float* __restrict__ gamma, const float* __restrict__ beta,
    const int* __restrict__ scls_g, float* __restrict__ M)
{
  __shared__ unsigned short sX[4 * 64 * 8];      // 4 KB  [g][rr][e]
  __shared__ unsigned short sW[4 * 512 * 8];     // 32 KB [g][n][e]
  __shared__ float wsum[4][64];
  __shared__ float wsq[4][64];
  __shared__ float smean[64];
  __shared__ float srstd[64];
  __shared__ int scls[64];
  __shared__ int run_start[65];
  __shared__ int run_cls[64];
  __shared__ int nruns_s;

  const int t = threadIdx.x;
  const int wv = t >> 6;
  const int lane = t & 63;
  const int lr = lane & 15;
  const int lq = lane >> 4;
  const int l = blockIdx.x;
  const int tile = blockIdx.y;
  const int row0 = tile * 64;

  const unsigned short* xsrc = XbT + (size_t)tile * 32768;        // tile*64*512
  const unsigned short* wsrc = W1T + (size_t)l * 262144;          // l*16*16384

  f32x4 acc[4][8];
  #pragma unroll
  for (int i = 0; i < 4; ++i)
    #pragma unroll
    for (int j = 0; j < 8; ++j) acc[i][j] = (f32x4){0.f, 0.f, 0.f, 0.f};

  if (t < 64) scls[t] = scls_g[row0 + t];

  unsigned short* sXw = sX + wv * 512;               // wave base, +lane*16B
  for (int ks = 0; ks < 16; ++ks) {
    gload16(xsrc + (size_t)ks * 2048 + t * 8, sXw);
    #pragma unroll
    for (int i = 0; i < 8; ++i)
      gload16(wsrc + (size_t)ks * 16384 + (i * 256 + t) * 8, sW + (i * 256 + wv * 64) * 8);
    __syncthreads();

    bf16x8 a[4], b[8];
    #pragma unroll
    for (int rf = 0; rf < 4; ++rf)
      a[rf] = *(const bf16x8*)(sX + (lq * 64 + rf * 16 + lr) * 8);
    #pragma unroll
    for (int cf = 0; cf < 8; ++cf)
      b[cf] = *(const bf16x8*)(sW + (lq * 512 + wv * 128 + cf * 16 + lr) * 8);

    #pragma unroll
    for (int rf = 0; rf < 4; ++rf)
      #pragma unroll
      for (int cf = 0; cf < 8; ++cf)
        acc[rf][cf] = __builtin_amdgcn_mfma_f32_16x16x32_bf16(a[rf], b[cf], acc[rf][cf], 0, 0, 0);
    __syncthreads();
  }

  // epilogue: bias + LN stats
  float b1v[8], gv[8], bv[8];
  #pragma unroll
  for (int cf = 0; cf < 8; ++cf) {
    const int col = wv * 128 + cf * 16 + lr;
    b1v[cf] = b1[l * 512 + col];
    gv[cf] = gamma[l * 512 + col];
    bv[cf] = beta[l * 512 + col];
  }
  #pragma unroll
  for (int rf = 0; rf < 4; ++rf)
    #pragma unroll
    for (int cf = 0; cf < 8; ++cf)
      #pragma unroll
      for (int j = 0; j < 4; ++j) acc[rf][cf][j] += b1v[cf];

  #pragma unroll
  for (int rf = 0; rf < 4; ++rf) {
    #pragma unroll
    for (int j = 0; j < 4; ++j) {
      float s = 0.f, q = 0.f;
      #pragma unroll
      for (int cf = 0; cf < 8; ++cf) { float v = acc[rf][cf][j]; s += v; q += v * v; }
      #pragma unroll
      for (int m = 8; m >= 1; m >>= 1) { s += __shfl_xor(s, m, 16); q += __shfl_xor(q, m, 16); }
      if (lr == 0) { const int row = rf * 16 + lq * 4 + j; wsum[wv][row] = s; wsq[wv][row] = q; }
    }
  }
  __syncthreads();
  if (t < 64) {
    const float s = wsum[0][t] + wsum[1][t] + wsum[2][t] + wsum[3][t];
    const float q = wsq[0][t] + wsq[1][t] + wsq[2][t] + wsq[3][t];
    const float mean = s * (1.0f / 512.0f);
    const float var = q * (1.0f / 512.0f) - mean * mean;
    smean[t] = mean;
    srstd[t] = rsqrtf(var + LN_EPS);
  }
  if (t == 0) {
    int n = 0;
    run_start[0] = 0;
    run_cls[0] = scls[0];
    for (int r = 1; r < 64; ++r) {
      if (scls[r] != scls[r - 1]) { ++n; run_start[n] = r; run_cls[n] = scls[r]; }
    }
    nruns_s = n + 1;
    run_start[n + 1] = 64;
  }
  __syncthreads();

  // finalize g = relu(LN(h)) in registers
  #pragma unroll
  for (int rf = 0; rf < 4; ++rf) {
    #pragma unroll
    for (int j = 0; j < 4; ++j) {
      const int row = rf * 16 + lq * 4 + j;
      const float mean = smean[row], rs = srstd[row];
      #pragma unroll
      for (int cf = 0; cf < 8; ++cf) {
        float v = (acc[rf][cf][j] - mean) * rs * gv[cf] + bv[cf];
        acc[rf][cf][j] = fmaxf(v, 0.f);
      }
    }
  }

  // per-run column sums -> atomicAdd into M[l][cls][col]
  const int nruns = nruns_s;
  float* Ml = M + (size_t)l * NUM_CLASSES * DIM;
  for (int r = 0; r < nruns; ++r) {
    const int rs = run_start[r], re = run_start[r + 1];
    const int cls = run_cls[r];
    float p[8];
    #pragma unroll
    for (int cf = 0; cf < 8; ++cf) p[cf] = 0.f;
    #pragma unroll
    for (int rf = 0; rf < 4; ++rf) {
      #pragma unroll
      for (int j = 0; j < 4; ++j) {
        const int row = rf * 16 + lq * 4 + j;
        if (row >= rs && row < re) {
          #pragma unroll
          for (int cf = 0; cf < 8; ++cf) p[cf] += acc[rf][cf][j];
        }
      }
    }
    #pragma unroll
    for (int cf = 0; cf < 8; ++cf) {
      p[cf] += __shfl_xor(p[cf], 16);
      p[cf] += __shfl_xor(p[cf], 32);
    }
    if (lq == 0) {
      #pragma unroll
      for (int cf = 0; cf < 8; ++cf)
        atomicAdd(&Ml[(size_t)cls * DIM + wv * 128 + cf * 16 + lr], p[cf]);
    }
  }
}

// ---------------- final GEMM: out += w_l * ((M_l/cnt) @ W2_l) (+ bias once) -------------
__global__ void k_final(const float* __restrict__ M, const float* __restrict__ W2,
                        const float* __restrict__ b2, const float* __restrict__ temps,
                        const float* __restrict__ invc, float* __restrict__ out)
{
  __shared__ float sA[64][17];
  __shared__ float sB[16][65];
  const int t = threadIdx.x;
  const int tx = t & 15, ty = t >> 4;
  const int bcol = blockIdx.x * 64;
  const int brow = blockIdx.y * 64;
  const int l = blockIdx.z;

  const float t0 = temps[0], t1 = temps[1], t2 = temps[2];
  const float mx = fmaxf(t0, fmaxf(t1, t2));
  const float e0 = expf(t0 - mx), e1 = expf(t1 - mx), e2 = expf(t2 - mx);
  const float inv = 1.f / (e0 + e1 + e2);
  const float w[3] = {e0 * inv, e1 * inv, e2 * inv};
  const float wl = w[l];

  float acc[4][4] = {};
  for (int k0 = 0; k0 < 512; k0 += 16) {
    __syncthreads();
    #pragma unroll
    for (int i = 0; i < 4; ++i) {
      const int e = i * 256 + t;
      const int r = e >> 4, k = e & 15;
      sA[r][k] = M[((size_t)l * 1024 + brow + r) * 512 + k0 + k] * (wl * invc[brow + r]);
    }
    #pragma unroll
    for (int i = 0; i < 4; ++i) {
      const int e = i * 256 + t;
      const int r = e >> 6, nn = e & 63;
      sB[r][nn] = W2[((size_t)l * 512 + k0 + r) * 512 + bcol + nn];
    }
    __syncthreads();
    #pragma unroll
    for (int kk = 0; kk < 16; ++kk) {
      float a[4], b[4];
      #pragma unroll
      for (int i = 0; i < 4; ++i) a[i] = sA[ty * 4 + i][kk];
      #pragma unroll
      for (int j = 0; j < 4; ++j) b[j] = sB[kk][tx * 4 + j];
      #pragma unroll
      for (int i = 0; i < 4; ++i)
        #pragma unroll
        for (int j = 0; j < 4; ++j) acc[i][j] += a[i] * b[j];
    }
  }
  #pragma unroll
  for (int j = 0; j < 4; ++j) {
    const int col = bcol + tx * 4 + j;
    const float bias = (l == 0)
        ? (w[0] * b2[col] + w[1] * b2[512 + col] + w[2] * b2[1024 + col]) : 0.f;
    #pragma unroll
    for (int i = 0; i < 4; ++i)
      atomicAdd(&out[(size_t)(brow + ty * 4 + i) * 512 + col], acc[i][j] + bias);
  }
}

extern "C" void kernel_launch(void* const* d_in, const int* in_sizes, int n_in,
                              void* d_out, int out_size, void* d_ws, size_t ws_size,
                              hipStream_t stream)
{
  const float* X = (const float*)d_in[0];
  const int* labels = (const int*)d_in[1];
  const float* W1 = (const float*)d_in[2];
  const float* b1 = (const float*)d_in[3];
  const float* gamma = (const float*)d_in[4];
  const float* beta = (const float*)d_in[5];
  const float* W2 = (const float*)d_in[6];
  const float* b2 = (const float*)d_in[7];
  const float* temps = (const float*)d_in[8];
  float* out = (float*)d_out;

  char* ws = (char*)d_ws;
  size_t off = 0;
  auto alloc = [&](size_t bytes) -> char* {
    char* p = ws + off;
    off += (bytes + 255) & ~(size_t)255;
    return p;
  };
  unsigned short* XbT = (unsigned short*)alloc((size_t)N_SUPPORT * DIM * 2);  // 128 MB, sorted+tiled
  unsigned short* W1T = (unsigned short*)alloc((size_t)3 * 512 * 512 * 2);
  float* M = (float*)alloc((size_t)3 * 1024 * 512 * 4);                       // 6 MB, atomic target
  int* counts = (int*)alloc(2048 * 4);       // counts[1024] + cursor[1024], one memset
  int* cursor = counts + 1024;
  int* offs = (int*)alloc(1024 * 4);
  float* invc = (float*)alloc(1024 * 4);
  int* sorted = (int*)alloc((size_t)N_SUPPORT * 4);
  int* scls = (int*)alloc((size_t)N_SUPPORT * 4);

  hipMemsetAsync(counts, 0, 2048 * 4, stream);
  hipMemsetAsync(M, 0, (size_t)3 * 1024 * 512 * 4, stream);
  hipMemsetAsync(out, 0, (size_t)NUM_CLASSES * DIM * 4, stream);
  k_hist<<<512, 256, 0, stream>>>(labels, counts);
  k_scan<<<1, 1024, 0, stream>>>(counts, offs, invc);
  k_scatter<<<512, 256, 0, stream>>>(labels, offs, cursor, sorted);
  k_cast_sorted<<<2048, 256, 0, stream>>>(X, sorted, labels, XbT, scls);
  k_prep_w1t<<<384, 256, 0, stream>>>(W1, W1T);
  k_gemm1lnred<<<dim3(3, 2048), 256, 0, stream>>>(XbT, W1T, b1, gamma, beta, scls, M);
  k_final<<<dim3(8, 16, 3), 256, 0, stream>>>(M, W2, b2, temps, invc, out);
}